// Round 1
// baseline (139.813 us; speedup 1.0000x reference)
//
#include <hip/hip_runtime.h>
#include <math.h>

#define NQ     10
#define DIM    1024
#define NFEAT  768
#define NT     256

struct C { float r, i; };
__device__ __forceinline__ C cadd(C a, C b){ return {a.r+b.r, a.i+b.i}; }
__device__ __forceinline__ C csub(C a, C b){ return {a.r-b.r, a.i-b.i}; }
__device__ __forceinline__ C cmul(C a, C b){ return {a.r*b.r - a.i*b.i, a.r*b.i + a.i*b.r}; }

// LDS skew: +1 slot every 32 elements breaks stride-2^k bank conflicts
__device__ __forceinline__ int IDXf(int i){ return i + (i >> 5); }

// Composite of the CNOT ring CNOT(0,1),CNOT(1,2),...,CNOT(9,0).
// s_after[j] = s_before[f(j)], f = sigma_10 ∘ ... applied innermost-first.
// CNOT(c,t): i ^= bit(i, 9-c) << (9-t). Order k=10..1 => (pc,pt):
// (0,9),(1,0),(2,1),(3,2),(4,3),(5,4),(6,5),(7,6),(8,7),(9,8)
__device__ __forceinline__ int cnot_perm(int j){
  int i = j;
  i ^= ((i >> 0) & 1) << 9;
  i ^= ((i >> 1) & 1) << 0;
  i ^= ((i >> 2) & 1) << 1;
  i ^= ((i >> 3) & 1) << 2;
  i ^= ((i >> 4) & 1) << 3;
  i ^= ((i >> 5) & 1) << 4;
  i ^= ((i >> 6) & 1) << 5;
  i ^= ((i >> 7) & 1) << 6;
  i ^= ((i >> 8) & 1) << 7;
  i ^= ((i >> 9) & 1) << 8;
  return i;
}

// generic complex 2x2 gate: a' = u00*a + u01*b ; b' = u10*a + u11*b
// U layout: u00r,u00i,u01r,u01i,u10r,u10i,u11r,u11i
__device__ __forceinline__ void applyU(const float* U, C& a, C& b){
  float ar=a.r, ai=a.i, br=b.r, bi=b.i;
  a.r = U[0]*ar - U[1]*ai + U[2]*br - U[3]*bi;
  a.i = U[0]*ai + U[1]*ar + U[2]*bi + U[3]*br;
  b.r = U[4]*ar - U[5]*ai + U[6]*br - U[7]*bi;
  b.i = U[4]*ai + U[5]*ar + U[6]*bi + U[7]*br;
}

// RY: a' = c*a - s*b ; b' = s*a + c*b  (real gate)
__device__ __forceinline__ void applyRY(float c, float s, C& a, C& b){
  float ar=a.r, ai=a.i, br=b.r, bi=b.i;
  a.r = c*ar - s*br; a.i = c*ai - s*bi;
  b.r = s*ar + c*br; b.i = s*ai + c*bi;
}

__global__ void __launch_bounds__(NT)
qqk_kernel(const float* __restrict__ x, const float* __restrict__ w,
           float* __restrict__ out)
{
  __shared__ float sre[1056];         // 1024 + skew
  __shared__ float sim[1056];
  __shared__ float gU[10][8];         // combined RZ*RY*RX per qubit
  __shared__ float gRY[10][2];        // final RY layer: cos, sin
  __shared__ float wred[4];
  __shared__ float esum[3][10][4];    // kind(X/Y/Z) x qubit x wave partials

  const int b    = blockIdx.x;
  const int t    = threadIdx.x;
  const int wave = t >> 6;
  const int lane = t & 63;

  // ---- build gate matrices (threads 0..9) ----
  if (t < 10) {
    float ha = 0.5f*w[t*4+0], hb = 0.5f*w[t*4+1];
    float hg = 0.5f*w[t*4+2], hd = 0.5f*w[t*4+3];
    float ca = cosf(ha), sa = sinf(ha);
    float cb = cosf(hb), sb = sinf(hb);
    float cg = cosf(hg), sg = sinf(hg);
    // RX = [[ca,-i sa],[-i sa, ca]], RY = [[cb,-sb],[sb,cb]], RZ = diag(e^-i hg, e^+i hg)
    C rx00={ca,0.f}, rx01={0.f,-sa}, rx10={0.f,-sa}, rx11={ca,0.f};
    C ry00={cb,0.f}, ry01={-sb,0.f}, ry10={sb,0.f},  ry11={cb,0.f};
    C m00 = cadd(cmul(ry00,rx00), cmul(ry01,rx10));
    C m01 = cadd(cmul(ry00,rx01), cmul(ry01,rx11));
    C m10 = cadd(cmul(ry10,rx00), cmul(ry11,rx10));
    C m11 = cadd(cmul(ry10,rx01), cmul(ry11,rx11));
    C e0 = {cg,-sg}, e1 = {cg, sg};
    C u00 = cmul(e0,m00), u01 = cmul(e0,m01);
    C u10 = cmul(e1,m10), u11 = cmul(e1,m11);
    gU[t][0]=u00.r; gU[t][1]=u00.i; gU[t][2]=u01.r; gU[t][3]=u01.i;
    gU[t][4]=u10.r; gU[t][5]=u10.i; gU[t][6]=u11.r; gU[t][7]=u11.i;
    gRY[t][0] = cosf(hd); gRY[t][1] = sinf(hd);
  }

  // ---- load x, pad to 1024, compute norm ----
  const float* xb = x + (size_t)b * NFEAT;
  float v0 = xb[t], v1 = xb[t+256], v2 = xb[t+512];
  sre[IDXf(t)]     = v0;
  sre[IDXf(t+256)] = v1;
  sre[IDXf(t+512)] = v2;
  sre[IDXf(t+768)] = 0.f;
  float ss = v0*v0 + v1*v1 + v2*v2;
  #pragma unroll
  for (int m = 1; m < 64; m <<= 1) ss += __shfl_xor(ss, m);
  if (lane == 0) wred[wave] = ss;
  __syncthreads();
  const float nrm  = sqrtf(wred[0] + wred[1] + wred[2] + wred[3]);
  const float invn = 1.0f / fmaxf(nrm, 1e-8f);

  // ---- combined RZ*RY*RX: 5 passes, 2 qubits each (bit pair P, P-1) ----
  #pragma unroll
  for (int k = 0; k < 5; ++k) {
    const int P = 9 - 2*k;                 // qubit 2k at bit P, qubit 2k+1 at bit P-1
    const int lowmask = (1 << (P-1)) - 1;
    const int base = (t & lowmask) | ((t >> (P-1)) << (P+1));
    const int i0 = IDXf(base);
    const int i1 = IDXf(base + (1 << (P-1)));
    const int i2 = IDXf(base + (1 << P));
    const int i3 = IDXf(base + (1 << P) + (1 << (P-1)));
    C x0, x1, x2, x3;
    if (k == 0) {  // state is real here; fold in 1/norm
      x0 = {sre[i0]*invn, 0.f}; x1 = {sre[i1]*invn, 0.f};
      x2 = {sre[i2]*invn, 0.f}; x3 = {sre[i3]*invn, 0.f};
    } else {
      x0 = {sre[i0], sim[i0]}; x1 = {sre[i1], sim[i1]};
      x2 = {sre[i2], sim[i2]}; x3 = {sre[i3], sim[i3]};
    }
    applyU(gU[2*k],   x0, x2); applyU(gU[2*k],   x1, x3);   // bit P
    applyU(gU[2*k+1], x0, x1); applyU(gU[2*k+1], x2, x3);   // bit P-1
    sre[i0]=x0.r; sim[i0]=x0.i;  sre[i1]=x1.r; sim[i1]=x1.i;
    sre[i2]=x2.r; sim[i2]=x2.i;  sre[i3]=x3.r; sim[i3]=x3.i;
    __syncthreads();
  }

  // ---- CNOT ring (folded into pass 0 reads) + final RY layer: 5 passes ----
  #pragma unroll
  for (int k = 0; k < 5; ++k) {
    const int P = 9 - 2*k;
    const int lowmask = (1 << (P-1)) - 1;
    const int base = (t & lowmask) | ((t >> (P-1)) << (P+1));
    const int j0 = base;
    const int j1 = base + (1 << (P-1));
    const int j2 = base + (1 << P);
    const int j3 = j2 + (1 << (P-1));
    C x0, x1, x2, x3;
    if (k == 0) {  // cross-thread permuted gather: read-all, barrier, then write
      const int r0 = IDXf(cnot_perm(j0)), r1 = IDXf(cnot_perm(j1));
      const int r2 = IDXf(cnot_perm(j2)), r3 = IDXf(cnot_perm(j3));
      x0 = {sre[r0], sim[r0]}; x1 = {sre[r1], sim[r1]};
      x2 = {sre[r2], sim[r2]}; x3 = {sre[r3], sim[r3]};
      __syncthreads();
    } else {
      const int i0 = IDXf(j0), i1 = IDXf(j1), i2 = IDXf(j2), i3 = IDXf(j3);
      x0 = {sre[i0], sim[i0]}; x1 = {sre[i1], sim[i1]};
      x2 = {sre[i2], sim[i2]}; x3 = {sre[i3], sim[i3]};
    }
    const float c0 = gRY[2*k][0],   s0 = gRY[2*k][1];
    const float c1 = gRY[2*k+1][0], s1 = gRY[2*k+1][1];
    applyRY(c0, s0, x0, x2); applyRY(c0, s0, x1, x3);
    applyRY(c1, s1, x0, x1); applyRY(c1, s1, x2, x3);
    const int i0 = IDXf(j0), i1 = IDXf(j1), i2 = IDXf(j2), i3 = IDXf(j3);
    sre[i0]=x0.r; sim[i0]=x0.i;  sre[i1]=x1.r; sim[i1]=x1.i;
    sre[i2]=x2.r; sim[i2]=x2.i;  sre[i3]=x3.r; sim[i3]=x3.i;
    __syncthreads();
  }

  // ---- 1024-pt FFT, positive exponent, DIF, two radix-2 stages per pass ----
  // output ends up bit-reversed; expectations compensate (qubit q <-> g-bit q)
  #pragma unroll
  for (int k = 0; k < 5; ++k) {
    const int P = 9 - 2*k;                 // stage spans 2^P then 2^(P-1)
    const int lowmask = (1 << (P-1)) - 1;
    const int base = (t & lowmask) | ((t >> (P-1)) << (P+1));
    const int i0 = IDXf(base);
    const int i1 = IDXf(base + (1 << (P-1)));
    const int i2 = IDXf(base + (1 << P));
    const int i3 = IDXf(base + (1 << P) + (1 << (P-1)));
    C x0 = {sre[i0], sim[i0]}, x1 = {sre[i1], sim[i1]};
    C x2 = {sre[i2], sim[i2]}, x3 = {sre[i3], sim[i3]};
    const int e = (t & lowmask) << (9 - P);          // twiddle exponent, T(e)=exp(+2pi i e/1024)
    float s1v, c1v;
    __sincosf((float)e * 6.13592315154256e-3f, &s1v, &c1v);  // 2*pi/1024
    const C tA = {c1v, s1v};
    C u0 = cadd(x0, x2);
    C w2 = cmul(csub(x0, x2), tA);
    C u1 = cadd(x1, x3);
    C w3t = cmul(csub(x1, x3), tA);
    C w3 = {-w3t.i, w3t.r};                          // * T(256) = i
    const C tB = {c1v*c1v - s1v*s1v, 2.f*c1v*s1v};   // T(2e)
    C y0 = cadd(u0, u1);
    C y1 = cmul(csub(u0, u1), tB);
    C y2 = cadd(w2, w3);
    C y3 = cmul(csub(w2, w3), tB);
    sre[i0]=y0.r; sim[i0]=y0.i;  sre[i1]=y1.r; sim[i1]=y1.i;
    sre[i2]=y2.r; sim[i2]=y2.i;  sre[i3]=y3.r; sim[i3]=y3.i;
    __syncthreads();
  }

  // ---- expectations: 5 read-only passes, 2 qubits each ----
  // g is bit-reversed => true qubit q pairs differ in g-bit q, stride 2^q
  #pragma unroll
  for (int k = 0; k < 5; ++k) {
    const int q = 2*k;
    const int lowmask = (1 << q) - 1;
    const int base = (t & lowmask) | ((t >> q) << (q+2));
    const int i0 = IDXf(base);
    const int i1 = IDXf(base + (1 << q));    // bit q set   (qubit q "b")
    const int i2 = IDXf(base + (2 << q));    // bit q+1 set (qubit q+1 "b")
    const int i3 = IDXf(base + (3 << q));
    C x0 = {sre[i0], sim[i0]}, x1 = {sre[i1], sim[i1]};
    C x2 = {sre[i2], sim[i2]}, x3 = {sre[i3], sim[i3]};
    const float n0 = x0.r*x0.r + x0.i*x0.i;
    const float n1 = x1.r*x1.r + x1.i*x1.i;
    const float n2 = x2.r*x2.r + x2.i*x2.i;
    const float n3 = x3.r*x3.r + x3.i*x3.i;
    // qubit q: pairs (x0,x1),(x2,x3)
    float xr  = x0.r*x1.r + x0.i*x1.i + x2.r*x3.r + x2.i*x3.i;
    float xi  = x0.r*x1.i - x0.i*x1.r + x2.r*x3.i - x2.i*x3.r;
    float zz  = (n0 + n2) - (n1 + n3);
    // qubit q+1: pairs (x0,x2),(x1,x3)
    float xr2 = x0.r*x2.r + x0.i*x2.i + x1.r*x3.r + x1.i*x3.i;
    float xi2 = x0.r*x2.i - x0.i*x2.r + x1.r*x3.i - x1.i*x3.r;
    float zz2 = (n0 + n1) - (n2 + n3);
    #pragma unroll
    for (int m = 1; m < 64; m <<= 1) {
      xr  += __shfl_xor(xr,  m); xi  += __shfl_xor(xi,  m); zz  += __shfl_xor(zz,  m);
      xr2 += __shfl_xor(xr2, m); xi2 += __shfl_xor(xi2, m); zz2 += __shfl_xor(zz2, m);
    }
    if (lane == 0) {
      esum[0][q][wave]   = xr;  esum[1][q][wave]   = xi;  esum[2][q][wave]   = zz;
      esum[0][q+1][wave] = xr2; esum[1][q+1][wave] = xi2; esum[2][q+1][wave] = zz2;
    }
  }
  __syncthreads();

  // out layout: cols 0..9 = <X_q>, 10..19 = <Y_q>, 20..29 = <Z_q>
  // scale: FFT omitted 1/32 per state => 1/1024 on quadratic forms; X/Y get extra 2x
  if (t < 30) {
    const int kind = t / 10, q = t % 10;
    float v = esum[kind][q][0] + esum[kind][q][1] + esum[kind][q][2] + esum[kind][q][3];
    const float scale = (kind == 2) ? (1.0f/1024.0f) : (2.0f/1024.0f);
    out[(size_t)b * 30 + t] = v * scale;
  }
}

extern "C" void kernel_launch(void* const* d_in, const int* in_sizes, int n_in,
                              void* d_out, int out_size, void* d_ws, size_t ws_size,
                              hipStream_t stream) {
  const float* x = (const float*)d_in[0];
  const float* w = (const float*)d_in[1];
  float* out = (float*)d_out;
  const int B = in_sizes[0] / NFEAT;   // 8192
  qqk_kernel<<<B, NT, 0, stream>>>(x, w, out);
}

// Round 2
// 67.192 us; speedup vs baseline: 2.0808x; 2.0808x over previous
//
#include <hip/hip_runtime.h>
#include <math.h>

#define NFEAT 768
#define NT    256

struct C { float r, i; };

// GF2-linear LDS swizzle on the complex index: spreads every pass's stride
// pattern (1,4,16,64,256) across all 16 bank-pairs within 16 lanes.
__device__ __forceinline__ int swz(int j){ return j ^ (j >> 4) ^ ((j >> 2) & 0xC); }

// Composite of the CNOT ring CNOT(0,1),...,CNOT(9,0): s_after[j] = s_before[perm(j)].
// XOR-linear, so swz(perm(.)) keeps bank spread (rank-4 on low nibble, verified).
__device__ __forceinline__ int cnot_perm(int j){
  int i = j;
  i ^= ((i >> 0) & 1) << 9;
  i ^= ((i >> 1) & 1) << 0;
  i ^= ((i >> 2) & 1) << 1;
  i ^= ((i >> 3) & 1) << 2;
  i ^= ((i >> 4) & 1) << 3;
  i ^= ((i >> 5) & 1) << 4;
  i ^= ((i >> 6) & 1) << 5;
  i ^= ((i >> 7) & 1) << 6;
  i ^= ((i >> 8) & 1) << 7;
  i ^= ((i >> 9) & 1) << 8;
  return i;
}

// A = (u00r,u00i,u01r,u01i), B = (u10r,u10i,u11r,u11i)
__device__ __forceinline__ void applyU(const float4 A, const float4 B, C& a, C& b){
  const float ar=a.r, ai=a.i, br=b.r, bi=b.i;
  a.r = A.x*ar - A.y*ai + A.z*br - A.w*bi;
  a.i = A.x*ai + A.y*ar + A.z*bi + A.w*br;
  b.r = B.x*ar - B.y*ai + B.z*br - B.w*bi;
  b.i = B.x*ai + B.y*ar + B.z*bi + B.w*br;
}

__device__ __forceinline__ void applyRY(float c, float s, C& a, C& b){
  const float ar=a.r, ai=a.i, br=b.r, bi=b.i;
  a.r = c*ar - s*br; a.i = c*ai - s*bi;
  b.r = s*ar + c*br; b.i = s*ai + c*bi;
}

__global__ void __launch_bounds__(NT)
qqk_kernel(const float* __restrict__ x, const float* __restrict__ w,
           float* __restrict__ out)
{
  // buf: swizzled complex state in [0,1024); later aliased as the 12x260
  // float2 reduction matrix (state is dead by then).
  __shared__ float2 buf[12*260];
  __shared__ float4 gU4[10][2];      // combined RZ*RY*RX per qubit
  __shared__ float2 gRY2[10];        // final RY layer (cos, sin)
  __shared__ float  wred[4];

  const int b    = blockIdx.x;
  const int t    = threadIdx.x;
  const int wave = t >> 6;
  const int lane = t & 63;

  // ---- gate build (threads 0..9) ----
  if (t < 10) {
    float ha = 0.5f*w[t*4+0], hb = 0.5f*w[t*4+1];
    float hg = 0.5f*w[t*4+2], hd = 0.5f*w[t*4+3];
    float ca = cosf(ha), sa = sinf(ha);
    float cb = cosf(hb), sb = sinf(hb);
    float cg = cosf(hg), sg = sinf(hg);
    // M = RY*RX ; U = RZ*M
    C m00 = { cb*ca,       -sb*(-sa) * 0.f - cb*0.f }; // placeholder, compute explicitly below
    // explicit complex math (RX has -i*sa off-diagonals):
    // RY*RX: row0 = (cb*ca, -i*cb*sa) + (-sb)*(-i*sa, ca) -> m00 = cb*ca, m01 = -i*cb*sa - sb*ca... do it with C ops:
    C rx00={ca,0.f}, rx01={0.f,-sa}, rx10={0.f,-sa}, rx11={ca,0.f};
    C ry00={cb,0.f}, ry01={-sb,0.f}, ry10={sb,0.f},  ry11={cb,0.f};
    C a00 = { ry00.r*rx00.r - ry00.i*rx00.i + ry01.r*rx10.r - ry01.i*rx10.i,
              ry00.r*rx00.i + ry00.i*rx00.r + ry01.r*rx10.i + ry01.i*rx10.r };
    C a01 = { ry00.r*rx01.r - ry00.i*rx01.i + ry01.r*rx11.r - ry01.i*rx11.i,
              ry00.r*rx01.i + ry00.i*rx01.r + ry01.r*rx11.i + ry01.i*rx11.r };
    C a10 = { ry10.r*rx00.r - ry10.i*rx00.i + ry11.r*rx10.r - ry11.i*rx10.i,
              ry10.r*rx00.i + ry10.i*rx00.r + ry11.r*rx10.i + ry11.i*rx10.r };
    C a11 = { ry10.r*rx01.r - ry10.i*rx01.i + ry11.r*rx11.r - ry11.i*rx11.i,
              ry10.r*rx01.i + ry10.i*rx01.r + ry11.r*rx11.i + ry11.i*rx11.r };
    (void)m00;
    // RZ = diag(e0, e1), e0 = cg - i sg, e1 = cg + i sg
    C u00 = { cg*a00.r + sg*a00.i, cg*a00.i - sg*a00.r };
    C u01 = { cg*a01.r + sg*a01.i, cg*a01.i - sg*a01.r };
    C u10 = { cg*a10.r - sg*a10.i, cg*a10.i + sg*a10.r };
    C u11 = { cg*a11.r - sg*a11.i, cg*a11.i + sg*a11.r };
    gU4[t][0] = make_float4(u00.r, u00.i, u01.r, u01.i);
    gU4[t][1] = make_float4(u10.r, u10.i, u11.r, u11.i);
    gRY2[t]   = make_float2(cosf(hd), sinf(hd));
  }

  // ---- load x, pad to 1024, compute norm ----
  const float* xb = x + (size_t)b * NFEAT;
  const float v0 = xb[t], v1 = xb[t+256], v2 = xb[t+512];
  const int st = swz(t);
  buf[st]            = make_float2(v0, 0.f);
  buf[st ^ swz(256)] = make_float2(v1, 0.f);
  buf[st ^ swz(512)] = make_float2(v2, 0.f);
  buf[st ^ swz(768)] = make_float2(0.f, 0.f);
  float ss = v0*v0 + v1*v1 + v2*v2;
  #pragma unroll
  for (int m = 1; m < 64; m <<= 1) ss += __shfl_xor(ss, m);
  if (lane == 0) wred[wave] = ss;
  __syncthreads();
  const float nrm  = sqrtf(wred[0] + wred[1] + wred[2] + wred[3]);
  const float invn = 1.0f / fmaxf(nrm, 1e-8f);

  // ---- combined RZ*RY*RX: 5 passes, qubit pair at bits (P, P-1) ----
  #pragma unroll
  for (int k = 0; k < 5; ++k) {
    const int P = 9 - 2*k;
    const int h = 1 << (P-1), H = 1 << P;
    const int base = (t & (h-1)) | ((t >> (P-1)) << (P+1));
    const int i0 = swz(base);
    const int i1 = i0 ^ swz(h);
    const int i2 = i0 ^ swz(H);
    const int i3 = i0 ^ swz(h) ^ swz(H);
    const float4 A0 = gU4[2*k][0],   B0 = gU4[2*k][1];
    const float4 A1 = gU4[2*k+1][0], B1 = gU4[2*k+1][1];
    float2 r0 = buf[i0], r1 = buf[i1], r2 = buf[i2], r3 = buf[i3];
    C x0, x1, x2, x3;
    if (k == 0) {   // state is real; fold 1/norm
      x0 = {r0.x*invn, 0.f}; x1 = {r1.x*invn, 0.f};
      x2 = {r2.x*invn, 0.f}; x3 = {r3.x*invn, 0.f};
    } else {
      x0 = {r0.x, r0.y}; x1 = {r1.x, r1.y};
      x2 = {r2.x, r2.y}; x3 = {r3.x, r3.y};
    }
    applyU(A0, B0, x0, x2); applyU(A0, B0, x1, x3);   // bit P
    applyU(A1, B1, x0, x1); applyU(A1, B1, x2, x3);   // bit P-1
    buf[i0] = make_float2(x0.r, x0.i); buf[i1] = make_float2(x1.r, x1.i);
    buf[i2] = make_float2(x2.r, x2.i); buf[i3] = make_float2(x3.r, x3.i);
    __syncthreads();
  }

  // ---- CNOT ring (gather in pass 0) + final RY layer: 5 passes ----
  #pragma unroll
  for (int k = 0; k < 5; ++k) {
    const int P = 9 - 2*k;
    const int h = 1 << (P-1), H = 1 << P;
    const int base = (t & (h-1)) | ((t >> (P-1)) << (P+1));
    const int j0 = base, j1 = base + h, j2 = base + H, j3 = base + H + h;
    const int i0 = swz(j0);
    const int i1 = i0 ^ swz(h);
    const int i2 = i0 ^ swz(H);
    const int i3 = i0 ^ swz(h) ^ swz(H);
    float2 r0, r1, r2, r3;
    if (k == 0) {   // permuted gather; read-all, barrier, then write
      r0 = buf[swz(cnot_perm(j0))]; r1 = buf[swz(cnot_perm(j1))];
      r2 = buf[swz(cnot_perm(j2))]; r3 = buf[swz(cnot_perm(j3))];
      __syncthreads();
    } else {
      r0 = buf[i0]; r1 = buf[i1]; r2 = buf[i2]; r3 = buf[i3];
    }
    C x0{r0.x,r0.y}, x1{r1.x,r1.y}, x2{r2.x,r2.y}, x3{r3.x,r3.y};
    const float c0 = gRY2[2*k].x,   s0 = gRY2[2*k].y;
    const float c1 = gRY2[2*k+1].x, s1 = gRY2[2*k+1].y;
    applyRY(c0, s0, x0, x2); applyRY(c0, s0, x1, x3);
    applyRY(c1, s1, x0, x1); applyRY(c1, s1, x2, x3);
    buf[i0] = make_float2(x0.r, x0.i); buf[i1] = make_float2(x1.r, x1.i);
    buf[i2] = make_float2(x2.r, x2.i); buf[i3] = make_float2(x3.r, x3.i);
    __syncthreads();
  }

  // ---- expectation accumulators ----
  float xr[10], xi[10];
  float S = 0.f, zz0 = 0.f, zz1 = 0.f;

  // ---- 1024-pt FFT (positive exponent, DIF, 2 radix-2 stages per pass) ----
  // Output is bit-reversed: true qubit q <-> g-bit q. Pass k=4 fuses the
  // qubit-0/1 expectations and the per-thread probability sums (all <Z>).
  #pragma unroll
  for (int k = 0; k < 5; ++k) {
    const int P = 9 - 2*k;
    const int h = 1 << (P-1), H = 1 << P;
    const int base = (t & (h-1)) | ((t >> (P-1)) << (P+1));
    const int i0 = swz(base);
    const int i1 = i0 ^ swz(h);
    const int i2 = i0 ^ swz(H);
    const int i3 = i0 ^ swz(h) ^ swz(H);
    float2 r0 = buf[i0], r1 = buf[i1], r2 = buf[i2], r3 = buf[i3];
    C x0{r0.x,r0.y}, x1{r1.x,r1.y}, x2{r2.x,r2.y}, x3{r3.x,r3.y};
    float c1v = 1.f, s1v = 0.f;
    if (k < 4) {
      const int e = (t & (h-1)) << (9 - P);
      __sincosf((float)e * 6.13592315154256e-3f, &s1v, &c1v);  // 2*pi/1024
    }
    const C tA = {c1v, s1v};
    C u0  = {x0.r + x2.r, x0.i + x2.i};
    C d02 = {x0.r - x2.r, x0.i - x2.i};
    C w2  = {d02.r*tA.r - d02.i*tA.i, d02.r*tA.i + d02.i*tA.r};
    C u1  = {x1.r + x3.r, x1.i + x3.i};
    C d13 = {x1.r - x3.r, x1.i - x3.i};
    C w3t = {d13.r*tA.r - d13.i*tA.i, d13.r*tA.i + d13.i*tA.r};
    C w3  = {-w3t.i, w3t.r};                          // * i
    const C tB = {c1v*c1v - s1v*s1v, 2.f*c1v*s1v};    // tA^2
    C y0 = {u0.r + u1.r, u0.i + u1.i};
    C d01 = {u0.r - u1.r, u0.i - u1.i};
    C y1 = {d01.r*tB.r - d01.i*tB.i, d01.r*tB.i + d01.i*tB.r};
    C y2 = {w2.r + w3.r, w2.i + w3.i};
    C d23 = {w2.r - w3.r, w2.i - w3.i};
    C y3 = {d23.r*tB.r - d23.i*tB.i, d23.r*tB.i + d23.i*tB.r};
    if (k == 4) {   // g-indices 4t..4t+3 in y0..y3: fused expectations
      const float n0 = y0.r*y0.r + y0.i*y0.i;
      const float n1 = y1.r*y1.r + y1.i*y1.i;
      const float n2 = y2.r*y2.r + y2.i*y2.i;
      const float n3 = y3.r*y3.r + y3.i*y3.i;
      S   = n0 + n1 + n2 + n3;
      zz0 = (n0 + n2) - (n1 + n3);
      zz1 = (n0 + n1) - (n2 + n3);
      xr[0] = y0.r*y1.r + y0.i*y1.i + y2.r*y3.r + y2.i*y3.i;
      xi[0] = y0.r*y1.i - y0.i*y1.r + y2.r*y3.i - y2.i*y3.r;
      xr[1] = y0.r*y2.r + y0.i*y2.i + y1.r*y3.r + y1.i*y3.i;
      xi[1] = y0.r*y2.i - y0.i*y2.r + y1.r*y3.i - y1.i*y3.r;
    }
    buf[i0] = make_float2(y0.r, y0.i); buf[i1] = make_float2(y1.r, y1.i);
    buf[i2] = make_float2(y2.r, y2.i); buf[i3] = make_float2(y3.r, y3.i);
    __syncthreads();
  }

  // ---- remaining expectations: qubits 2..9, 4 read-only passes, no barriers ----
  #pragma unroll
  for (int kk = 1; kk < 5; ++kk) {
    const int q = 2*kk;
    const int h = 1 << q, H = 2 << q;
    const int base = (t & (h-1)) | ((t >> q) << (q+2));
    const int i0 = swz(base);
    const int i1 = i0 ^ swz(h);
    const int i2 = i0 ^ swz(H);
    const int i3 = i0 ^ swz(h) ^ swz(H);
    const float2 a0 = buf[i0], a1 = buf[i1], a2 = buf[i2], a3 = buf[i3];
    xr[q]   = a0.x*a1.x + a0.y*a1.y + a2.x*a3.x + a2.y*a3.y;
    xi[q]   = a0.x*a1.y - a0.y*a1.x + a2.x*a3.y - a2.y*a3.x;
    xr[q+1] = a0.x*a2.x + a0.y*a2.y + a1.x*a3.x + a1.y*a3.y;
    xi[q+1] = a0.x*a2.y - a0.y*a2.x + a1.x*a3.y - a1.y*a3.x;
  }
  __syncthreads();   // state reads done; buf becomes the reduction matrix

  // ---- stage 1: write per-thread partials: 12 rows x 256 cols of float2 ----
  #pragma unroll
  for (int r = 0; r < 10; ++r) buf[r*260 + t] = make_float2(xr[r], xi[r]);
  buf[10*260 + t] = make_float2(zz0, zz1);
  buf[11*260 + t] = make_float2(S, 0.f);
  __syncthreads();

  // ---- stage 2: 192 threads, 16 per row ----
  if (t < 192) {
    const int r = t >> 4, j = t & 15;
    float* ob = out + (size_t)b * 30;
    if (r == 11) {
      // Walsh-Hadamard over column bits of the probability sums -> Z_2..Z_9
      float s = 0.f, t4 = 0.f, t5 = 0.f, t6 = 0.f, t7 = 0.f;
      #pragma unroll
      for (int i = 0; i < 16; ++i) {
        const float v = buf[11*260 + j + 16*i].x;
        s  += v;
        t4 += (i & 1) ? -v : v;
        t5 += (i & 2) ? -v : v;
        t6 += (i & 4) ? -v : v;
        t7 += (i & 8) ? -v : v;
      }
      float wv;
      wv = __shfl_xor(s, 1); float d0 = (j & 1) ? (wv - s) : (s - wv); s += wv;
      wv = __shfl_xor(s, 2); float d1 = (j & 2) ? (wv - s) : (s - wv); s += wv;
      wv = __shfl_xor(s, 4); float d2 = (j & 4) ? (wv - s) : (s - wv); s += wv;
      wv = __shfl_xor(s, 8); float d3 = (j & 8) ? (wv - s) : (s - wv); s += wv;
      d0 += __shfl_xor(d0, 2); d0 += __shfl_xor(d0, 4); d0 += __shfl_xor(d0, 8);
      d1 += __shfl_xor(d1, 4); d1 += __shfl_xor(d1, 8);
      d2 += __shfl_xor(d2, 8);
      t4 += __shfl_xor(t4, 1); t4 += __shfl_xor(t4, 2); t4 += __shfl_xor(t4, 4); t4 += __shfl_xor(t4, 8);
      t5 += __shfl_xor(t5, 1); t5 += __shfl_xor(t5, 2); t5 += __shfl_xor(t5, 4); t5 += __shfl_xor(t5, 8);
      t6 += __shfl_xor(t6, 1); t6 += __shfl_xor(t6, 2); t6 += __shfl_xor(t6, 4); t6 += __shfl_xor(t6, 8);
      t7 += __shfl_xor(t7, 1); t7 += __shfl_xor(t7, 2); t7 += __shfl_xor(t7, 4); t7 += __shfl_xor(t7, 8);
      if (j == 0) {
        const float zs = 1.0f/1024.0f;
        ob[22] = d0*zs; ob[23] = d1*zs; ob[24] = d2*zs; ob[25] = d3*zs;
        ob[26] = t4*zs; ob[27] = t5*zs; ob[28] = t6*zs; ob[29] = t7*zs;
      }
    } else {
      float ax = 0.f, ay = 0.f;
      #pragma unroll
      for (int i = 0; i < 16; ++i) {
        const float2 v = buf[r*260 + j + 16*i];
        ax += v.x; ay += v.y;
      }
      ax += __shfl_xor(ax, 1); ay += __shfl_xor(ay, 1);
      ax += __shfl_xor(ax, 2); ay += __shfl_xor(ay, 2);
      ax += __shfl_xor(ax, 4); ay += __shfl_xor(ay, 4);
      ax += __shfl_xor(ax, 8); ay += __shfl_xor(ay, 8);
      if (j == 0) {
        if (r < 10) { ob[r] = ax * (2.0f/1024.0f); ob[10+r] = ay * (2.0f/1024.0f); }
        else        { ob[20] = ax * (1.0f/1024.0f); ob[21] = ay * (1.0f/1024.0f); }
      }
    }
  }
}

extern "C" void kernel_launch(void* const* d_in, const int* in_sizes, int n_in,
                              void* d_out, int out_size, void* d_ws, size_t ws_size,
                              hipStream_t stream) {
  const float* x = (const float*)d_in[0];
  const float* w = (const float*)d_in[1];
  float* out = (float*)d_out;
  const int B = in_sizes[0] / NFEAT;   // 8192
  qqk_kernel<<<B, NT, 0, stream>>>(x, w, out);
}